// Round 14
// baseline (4347.711 us; speedup 1.0000x reference)
//
#include <hip/hip_runtime.h>
#include <math.h>

#define BATCH   8
#define NPTS    32768
#define FDIM    32
#define NGROUP  1024
#define GSIZE   32
#define KLANE   8       // per-lane candidate list length in KNN

// FPS: 8 blocks/batch x 512 thr x 8 pts/thr = 32768.
#define NBLK    8
#define FTPB    512
#define CHUNK   (NPTS / NBLK)     // 4096 points per block
#define NFPSBLK (BATCH * NBLK)    // 64 producer blocks (first in grid)
#define KNNQPB  8                 // 8 queries (waves) per 512-thr knn block
#define NKNNBLK ((BATCH * NGROUP) / KNNQPB)   // 1024 consumer blocks

typedef unsigned long long u64;

// Exact float32 distance in the reference's association: ((dx^2+dy^2)+dz^2),
// contraction blocked so bits match the numpy ref (argmax stability).
__device__ __forceinline__ float dist2f(float ax, float ay, float az,
                                        float bx, float by, float bz) {
  float dx = __fsub_rn(ax, bx);
  float dy = __fsub_rn(ay, by);
  float dz = __fsub_rn(az, bz);
  return __fadd_rn(__fadd_rn(__fmul_rn(dx, dx), __fmul_rn(dy, dy)),
                   __fmul_rn(dz, dz));
}

#define X8(M) M(0) M(1) M(2) M(3) M(4) M(5) M(6) M(7)

// ---------------------------------------------------------------------------
// Fused producer-consumer kernel.
// Producers (blocks 0..63): FPS with coords-in-payload consensus.
//   R13 post-mortem: the serial chain's reducible links are B2 + LDS bcast +
//   the dependent c3[gp] load (store->observe RT itself proved invariant
//   across R6/R7/R8/R12). Here each block publishes THREE self-tagged u64s
//   carrying dist/idx AND the candidate's exact coord bits:
//     S0 = t<<54 | dist<<22 | (0x7FFF-idx)<<7 | x[31:25]
//     S1 = t<<54 | x[24:0]<<29 | y[31:3]
//     S2 = t<<54 | y[2:0]<<32  | z
//   (u64 max on S0 == argmax with numpy lowest-index tie-break; low x bits
//   can't affect ties since block index ranges are disjoint.)
//   All waves poll the batch's 24 slots (lanes 0..23, relaxed; each word is
//   self-validating via its tag), ballot until all tags==t, 3-step butterfly
//   on the 8 S0s (+wbk carry), two shuffles fetch the winner's S1/S2 ->
//   coords in-register. One barrier per iteration (B1); no B2, no LDS
//   bcast, no dependent global coord load. Parity ping-pong (t&1) clobber
//   safety as before.
// Consumers (blocks 64..1087): R13 verbatim (conservative clock-safe
//   backoff, then s_sleep(64) spin on s_idx_ws[qid], idx+1 encoding).
// ---------------------------------------------------------------------------
__global__ __launch_bounds__(FTPB) void fused_kernel(
    const float* __restrict__ coord, const float* __restrict__ feat,
    const int* __restrict__ labels,
    u64* __restrict__ slots,                  // [2][BATCH][3][8] u64, zeroed
    int* __restrict__ s_idx_ws,               // [8192] idx+1, pre-zeroed
    float* __restrict__ out) {
  __shared__ float redv[8];
  __shared__ int   redp[8];
  __shared__ float redx[8], redy[8], redz[8];

  const int bx   = blockIdx.x;
  const int tid  = threadIdx.x;
  const int lane = tid & 63;
  const int wid  = tid >> 6;          // 0..7

  if (bx < NFPSBLK) {
    // ===================== FPS (producer) =====================
    const int b    = bx & 7;          // batch (XCD-local under %8 mapping)
    const int bk   = bx >> 3;         // block within batch
    const float* __restrict__ c = coord + (size_t)b * NPTS * 3;
    const float3* __restrict__ c3 = (const float3*)c;
    const int pbase = bk * CHUNK + tid;

#define DECL8(i) float x##i, y##i, z##i, d##i;
    X8(DECL8)
#undef DECL8

    // Init: distance to batch point 0; local argmax (ascending index +
    // strict > == np.argmax lowest-index tie-break).
    float qx = c[0], qy = c[1], qz = c[2];
    float bestv = -1.0f; int bestp = 0;
#define LOAD8(i) { int p = pbase + (i) * FTPB; float3 v = c3[p];            \
    x##i = v.x; y##i = v.y; z##i = v.z;                                      \
    float t2 = dist2f(v.x, v.y, v.z, qx, qy, qz); d##i = t2;                 \
    if (t2 > bestv) { bestv = t2; bestp = p; } }
    X8(LOAD8)
#undef LOAD8

    if (bk == 0 && tid == 0)
      __hip_atomic_store(&s_idx_ws[b * NGROUP + 0], 1, __ATOMIC_RELAXED,
                         __HIP_MEMORY_SCOPE_AGENT);   // idx 0, +1 encoding

    for (int t = 1; t < NGROUP; ++t) {
      // Wave-level argmax (max value, tie -> min index).
      float v = bestv; int p = bestp;
      #pragma unroll
      for (int m = 1; m < 64; m <<= 1) {
        float ov = __shfl_xor(v, m, 64);
        int   op = __shfl_xor(p, m, 64);
        if (ov > v || (ov == v && op < p)) { v = ov; p = op; }
      }
      // Recover the winning point's coords from its owner lane (p uniform).
      {
        int rel = p - bk * CHUNK;      // tid_owner + 512*i
        int ol  = rel & 63;            // owner lane in this wave
        int ii  = rel >> 9;            // register index 0..7 (uniform)
        float sx = 0.f, sy = 0.f, sz = 0.f;
#define SEL(i) if (ii == (i)) { sx = x##i; sy = y##i; sz = z##i; }
        X8(SEL)
#undef SEL
        sx = __shfl(sx, ol, 64); sy = __shfl(sy, ol, 64);
        sz = __shfl(sz, ol, 64);
        if (lane == 0) {
          redv[wid] = v; redp[wid] = p;
          redx[wid] = sx; redy[wid] = sy; redz[wid] = sz;
        }
      }
      __syncthreads();   // B1 (only barrier per iteration)

      u64* base = slots + ((size_t)(t & 1) * BATCH + b) * 24;
      if (wid == 0) {
        // Block-level argmax over 8 wave candidates, carrying source wave.
        int widx = lane & 7;
        float gvv = redv[widx]; int gpp = redp[widx]; int gw = widx;
        #pragma unroll
        for (int m = 1; m < 8; m <<= 1) {
          float ov = __shfl_xor(gvv, m, 64);
          int   op = __shfl_xor(gpp, m, 64);
          int   ow = __shfl_xor(gw, m, 64);
          if (ov > gvv || (ov == gvv && op < gpp)) { gvv = ov; gpp = op; gw = ow; }
        }
        if (lane == 0) {
          unsigned int xb = __float_as_uint(redx[gw]);
          unsigned int yb = __float_as_uint(redy[gw]);
          unsigned int zb = __float_as_uint(redz[gw]);
          unsigned int db = __float_as_uint(gvv);
          u64 S0 = ((u64)t << 54) | ((u64)db << 22)
                 | ((u64)(0x7FFF - gpp) << 7) | (u64)(xb >> 25);
          u64 S1 = ((u64)t << 54) | ((u64)(xb & 0x1FFFFFFu) << 29)
                 | (u64)(yb >> 3);
          u64 S2 = ((u64)t << 54) | ((u64)(yb & 7u) << 32) | (u64)zb;
          __hip_atomic_store(base + bk,      S0, __ATOMIC_RELAXED,
                             __HIP_MEMORY_SCOPE_AGENT);
          __hip_atomic_store(base + 8 + bk,  S1, __ATOMIC_RELAXED,
                             __HIP_MEMORY_SCOPE_AGENT);
          __hip_atomic_store(base + 16 + bk, S2, __ATOMIC_RELAXED,
                             __HIP_MEMORY_SCOPE_AGENT);
        }
      }

      // All waves: poll the 24 self-tagged slots (3 lines) until all == t.
      const int pl = (lane < 24) ? lane : 0;
      u64 pk2; bool ok;
      do {
        pk2 = __hip_atomic_load(base + pl, __ATOMIC_RELAXED,
                                __HIP_MEMORY_SCOPE_AGENT);
        ok = (lane >= 24) || ((int)(pk2 >> 54) == t);
      } while (__ballot(ok) != ~0ULL);

      // 8-way max over S0 (lanes hold S0 of block lane&7 via shuffle).
      u64 s0 = __shfl(pk2, lane & 7, 64);
      int wbk = lane & 7;
      #pragma unroll
      for (int m = 1; m < 8; m <<= 1) {
        u64 o  = __shfl_xor(s0, m, 64);
        int ob = __shfl_xor(wbk, m, 64);
        if (o > s0) { s0 = o; wbk = ob; }
      }
      const int gp = 0x7FFF - (int)((s0 >> 7) & 0x7FFF);
      u64 S1w = __shfl(pk2, 8 + wbk, 64);
      u64 S2w = __shfl(pk2, 16 + wbk, 64);
      unsigned int xb = (unsigned int)(((s0 & 0x7Fu) << 25)
                       | ((S1w >> 29) & 0x1FFFFFFu));
      unsigned int yb = (unsigned int)(((S1w & 0x1FFFFFFFu) << 3)
                       | ((S2w >> 32) & 0x7u));
      unsigned int zb = (unsigned int)(S2w & 0xFFFFFFFFu);

      if (bk == 0 && wid == 0 && lane == 0)
        __hip_atomic_store(&s_idx_ws[b * NGROUP + t], gp + 1,
                           __ATOMIC_RELAXED, __HIP_MEMORY_SCOPE_AGENT);
      if (t == NGROUP - 1) break;

      qx = __uint_as_float(xb);
      qy = __uint_as_float(yb);
      qz = __uint_as_float(zb);
      bestv = -1.0f; bestp = 0;
#define UPD8(i) { float t2 = dist2f(x##i, y##i, z##i, qx, qy, qz);           \
    float nd = fminf(d##i, t2); d##i = nd;                                   \
    if (nd > bestv) { bestv = nd; bestp = pbase + (i) * FTPB; } }
      X8(UPD8)
#undef UPD8
    }
    return;
  }

  // ===================== KNN (consumer) =====================
  const int qid = (bx - NFPSBLK) * KNNQPB + wid;   // 0..8191
  const int b   = qid >> 10;
  const float* __restrict__ c = coord + (size_t)b * NPTS * 3;

  // Conservative backoff (~1/3 of estimated publish time), then slow spin.
  const int tq = qid & (NGROUP - 1);
  int enc = __hip_atomic_load(&s_idx_ws[qid], __ATOMIC_RELAXED,
                              __HIP_MEMORY_SCOPE_AGENT);
  for (int i = tq >> 2; i > 0 && enc == 0; --i) {
    __builtin_amdgcn_s_sleep(127);
    enc = __hip_atomic_load(&s_idx_ws[qid], __ATOMIC_RELAXED,
                            __HIP_MEMORY_SCOPE_AGENT);
  }
  while (enc == 0) {
    __builtin_amdgcn_s_sleep(64);
    enc = __hip_atomic_load(&s_idx_ws[qid], __ATOMIC_RELAXED,
                            __HIP_MEMORY_SCOPE_AGENT);
  }
  const int sp = __builtin_amdgcn_readfirstlane(enc - 1);
  const int gq = b * NPTS + sp;
  const float qx = coord[(size_t)gq * 3 + 0];
  const float qy = coord[(size_t)gq * 3 + 1];
  const float qz = coord[(size_t)gq * 3 + 2];

  // Per-lane ascending top-8 (value, index), static indexing only.
  float lv[KLANE]; int li[KLANE];
  #pragma unroll
  for (int j = 0; j < KLANE; ++j) { lv[j] = 1e30f; li[j] = 0x7fffffff; }

  // Branchless sorted insert; strict < keeps equal-distance earlier (lower)
  // indices first, matching lax.top_k tie order.
#define INSERT(D2, P) \
  if ((D2) < lv[KLANE - 1]) { \
    _Pragma("unroll") \
    for (int j = KLANE - 1; j >= 1; --j) { \
      bool up = (D2) < lv[j - 1]; \
      float nv = up ? lv[j - 1] : (((D2) < lv[j]) ? (D2) : lv[j]); \
      int   ni = up ? li[j - 1] : (((D2) < lv[j]) ? (P)  : li[j]); \
      lv[j] = nv; li[j] = ni; \
    } \
    if ((D2) < lv[0]) { lv[0] = (D2); li[0] = (P); } \
  }

  for (int s = 0; s < NPTS / 256; ++s) {   // 128 iterations, 4 pts/lane
    int p = (s << 8) | (lane << 2);
    const float4* c4 = (const float4*)(c + (size_t)p * 3);
    float4 f0 = c4[0], f1 = c4[1], f2 = c4[2];
    float dA = dist2f(f0.x, f0.y, f0.z, qx, qy, qz);
    float dB = dist2f(f0.w, f1.x, f1.y, qx, qy, qz);
    float dC = dist2f(f1.z, f1.w, f2.x, qx, qy, qz);
    float dD = dist2f(f2.y, f2.z, f2.w, qx, qy, qz);
    INSERT(dA, p);
    INSERT(dB, p + 1);
    INSERT(dC, p + 2);
    INSERT(dD, p + 3);
  }
#undef INSERT

  // Extract the 32 globally smallest (ascending, tie -> lower index).
  // Round 0 is the query itself (d2 == 0), excluded from the angle mean
  // like angles[:, :, 1:].
  int nbp = 0;
  for (int r = 0; r < GSIZE; ++r) {
    float mv = lv[0]; int mp = li[0];
    #pragma unroll
    for (int m = 1; m < 64; m <<= 1) {
      float ov = __shfl_xor(mv, m, 64);
      int   op = __shfl_xor(mp, m, 64);
      if (ov < mv || (ov == mv && op < mp)) { mv = ov; mp = op; }
    }
    if (lane == r) nbp = mp;
    if (lv[0] == mv && li[0] == mp) {  // unique winner pops its head
      #pragma unroll
      for (int j = 0; j < KLANE - 1; ++j) { lv[j] = lv[j + 1]; li[j] = li[j + 1]; }
      lv[KLANE - 1] = 1e30f; li[KLANE - 1] = 0x7fffffff;
    }
  }

  // Angle for lanes 1..31: theta = 2*atan2(||a*|b| - |a|*b||, ||a*|b| + |a|*b||)
  const float* aRow = feat + (size_t)gq * FDIM;
  float my_a = (lane < FDIM) ? aRow[lane] : 0.0f;

  float ang = 0.0f;
  if (lane >= 1 && lane < GSIZE) {
    const float4* a4 = (const float4*)aRow;
    const float4* b4 = (const float4*)(feat + ((size_t)b * NPTS + nbp) * FDIM);
    float4 av[FDIM / 4], bv[FDIM / 4];
    float aa = 0.0f, bb = 0.0f;
    #pragma unroll
    for (int k = 0; k < FDIM / 4; ++k) {
      av[k] = a4[k]; bv[k] = b4[k];
      aa += av[k].x * av[k].x + av[k].y * av[k].y + av[k].z * av[k].z + av[k].w * av[k].w;
      bb += bv[k].x * bv[k].x + bv[k].y * bv[k].y + bv[k].z * bv[k].z + bv[k].w * bv[k].w;
    }
    float an = sqrtf(aa), bn = sqrtf(bb);
    float num2 = 0.0f, den2 = 0.0f;
    #pragma unroll
    for (int k = 0; k < FDIM / 4; ++k) {
      float n0 = av[k].x * bn - an * bv[k].x, dd0 = av[k].x * bn + an * bv[k].x;
      float n1 = av[k].y * bn - an * bv[k].y, dd1 = av[k].y * bn + an * bv[k].y;
      float n2 = av[k].z * bn - an * bv[k].z, dd2 = av[k].z * bn + an * bv[k].z;
      float n3 = av[k].w * bn - an * bv[k].w, dd3 = av[k].w * bn + an * bv[k].w;
      num2 += n0 * n0 + n1 * n1 + n2 * n2 + n3 * n3;
      den2 += dd0 * dd0 + dd1 * dd1 + dd2 * dd2 + dd3 * dd3;
    }
    ang = 2.0f * atan2f(sqrtf(num2), sqrtf(den2));
  }

  // Wave sum of the 31 angles -> p_curv everywhere.
  float tot = ang;
  #pragma unroll
  for (int m = 1; m < 64; m <<= 1) tot += __shfl_xor(tot, m, 64);
  float p_curv = tot / 31.0f;

  // Outputs (flat concatenation, all as float32).
  float* out_xyz  = out;                              // 8192*3
  float* out_feat = out + (size_t)BATCH * NGROUP * 3; // 8192*33
  float* out_sw   = out_feat + (size_t)BATCH * NGROUP * (FDIM + 1);
  float* out_lab  = out_sw  + (size_t)BATCH * NGROUP;
  float* out_sif  = out_lab + (size_t)BATCH * NGROUP;

  if (lane < FDIM)  out_feat[(size_t)qid * (FDIM + 1) + lane] = my_a;
  if (lane == FDIM) out_feat[(size_t)qid * (FDIM + 1) + FDIM] = p_curv;
  if (lane == 0) {
    out_xyz[(size_t)qid * 3 + 0] = qx;
    out_xyz[(size_t)qid * 3 + 1] = qy;
    out_xyz[(size_t)qid * 3 + 2] = qz;
    out_sw[qid]  = (p_curv > 0.087266f) ? 1.0f : 0.0f;
    out_lab[qid] = (float)labels[gq];
    out_sif[qid] = (float)gq;   // s_idx + b*N
  }
}

extern "C" void kernel_launch(void* const* d_in, const int* in_sizes, int n_in,
                              void* d_out, int out_size, void* d_ws, size_t ws_size,
                              hipStream_t stream) {
  const float* coord  = (const float*)d_in[0];
  const float* feat   = (const float*)d_in[1];
  const int*   labels = (const int*)d_in[2];

  // ws layout: [2][8][3][8] u64 self-tagged slots (3 KB), then [8192] int
  // s_idx (+1 encoded, 0 = unpublished). Both must start zeroed.
  u64* slots = (u64*)d_ws;
  int* s_idx_ws = (int*)((char*)d_ws + 2 * BATCH * 24 * sizeof(u64));
  const size_t zbytes = 2 * BATCH * 24 * sizeof(u64)
                      + (size_t)BATCH * NGROUP * sizeof(int);

  hipMemsetAsync(d_ws, 0, zbytes, stream);
  fused_kernel<<<NFPSBLK + NKNNBLK, FTPB, 0, stream>>>(
      coord, feat, labels, slots, s_idx_ws, (float*)d_out);
}

// Round 15
// 2882.096 us; speedup vs baseline: 1.5085x; 1.5085x over previous
//
#include <hip/hip_runtime.h>
#include <math.h>

#define BATCH   8
#define NPTS    32768
#define FDIM    32
#define NGROUP  1024
#define GSIZE   32
#define KLANE   8       // per-lane candidate list length in KNN

// FPS: 8 blocks/batch x 512 thr x 8 pts/thr = 32768.
#define NBLK    8
#define FTPB    512
#define CHUNK   (NPTS / NBLK)     // 4096 points per block
#define NFPSBLK (BATCH * NBLK)    // 64 producer blocks (first in grid)
#define KNNQPB  8                 // 8 queries (waves) per 512-thr knn block
#define NKNNBLK ((BATCH * NGROUP) / KNNQPB)   // 1024 consumer blocks

// Exact float32 distance in the reference's association: ((dx^2+dy^2)+dz^2),
// contraction blocked so bits match the numpy ref (argmax stability).
__device__ __forceinline__ float dist2f(float ax, float ay, float az,
                                        float bx, float by, float bz) {
  float dx = __fsub_rn(ax, bx);
  float dy = __fsub_rn(ay, by);
  float dz = __fsub_rn(az, bz);
  return __fadd_rn(__fadd_rn(__fmul_rn(dx, dx), __fmul_rn(dy, dy)),
                   __fmul_rn(dz, dz));
}

#define X8(M) M(0) M(1) M(2) M(3) M(4) M(5) M(6) M(7)

// ---------------------------------------------------------------------------
// Fused producer-consumer kernel. R13 verbatim (best measured: 2884 us).
// Consensus-structure search is closed: 6 variants (R6/R7/R8/R12/R13/R14)
// show a hard floor of ~2.6-2.9 us/iteration whenever exactly ONE cache
// line per batch must propagate per round; more lines (R14: 3) or more
// writers/pollers (R7: 64 slots, R12: hot counter) regress 1.5-4x. The
// floor is store->observe latency + 8-block straggler spread, not compute
// (update chain ~450 cyc ~= 1/6 of the period) and not intra-block
// mechanics (barriered R6 == barrier-free R8 within noise).
// Producers (blocks 0..63): FPS, one batch per XCD (gb&7 under %8 RR),
//   wave argmax -> B1 -> wid0 8-way reduce -> release-store packed
//   candidate (t<<47|dist<<15|0x7FFF-idx) -> lanes0..7 acquire-poll the
//   batch's 8 slots -> 8-max -> LDS bcast -> B2 -> dependent coord load.
//   Parity ping-pong (t&1) slots; publishes s_idx as idx+1.
// Consumers (blocks 64..1087): clock-safe backoff (~1/3 of estimated
//   publish time in s_sleep(127) chunks -- s_sleep counts CORE CLOCKS, so
//   near-deadline estimates oversleep at throttled clocks, R12 lesson),
//   then s_sleep(64) spin; float4 coord scan (4 pts/lane, 128 iters),
//   per-lane top-8 + 32 wave-argmin extractions, angle mean, 5 outputs.
// ---------------------------------------------------------------------------
__global__ __launch_bounds__(FTPB) void fused_kernel(
    const float* __restrict__ coord, const float* __restrict__ feat,
    const int* __restrict__ labels,
    unsigned long long* __restrict__ slots,   // [2][64] u64, pre-zeroed
    int* __restrict__ s_idx_ws,               // [8192] idx+1, pre-zeroed
    float* __restrict__ out) {
  __shared__ float redv[8];
  __shared__ int   redp[8];
  __shared__ unsigned long long bcast;

  const int bx   = blockIdx.x;
  const int tid  = threadIdx.x;
  const int lane = tid & 63;
  const int wid  = tid >> 6;          // 0..7

  if (bx < NFPSBLK) {
    // ===================== FPS (producer) =====================
    const int b    = bx & 7;          // batch (XCD-local under %8 mapping)
    const int bk   = bx >> 3;         // block within batch
    const float* __restrict__ c = coord + (size_t)b * NPTS * 3;
    const float3* __restrict__ c3 = (const float3*)c;
    const int pbase = bk * CHUNK + tid;

#define DECL8(i) float x##i, y##i, z##i, d##i;
    X8(DECL8)
#undef DECL8

    // Init: distance to batch point 0; local argmax (ascending index +
    // strict > == np.argmax lowest-index tie-break).
    float qx = c[0], qy = c[1], qz = c[2];
    float bestv = -1.0f; int bestp = 0;
#define LOAD8(i) { int p = pbase + (i) * FTPB; float3 v = c3[p];            \
    x##i = v.x; y##i = v.y; z##i = v.z;                                      \
    float t2 = dist2f(v.x, v.y, v.z, qx, qy, qz); d##i = t2;                 \
    if (t2 > bestv) { bestv = t2; bestp = p; } }
    X8(LOAD8)
#undef LOAD8

    if (bk == 0 && tid == 0)
      __hip_atomic_store(&s_idx_ws[b * NGROUP + 0], 1, __ATOMIC_RELAXED,
                         __HIP_MEMORY_SCOPE_AGENT);   // idx 0, +1 encoding

    for (int t = 1; t < NGROUP; ++t) {
      // Wave-level argmax (max value, tie -> min index).
      float v = bestv; int p = bestp;
      #pragma unroll
      for (int m = 1; m < 64; m <<= 1) {
        float ov = __shfl_xor(v, m, 64);
        int   op = __shfl_xor(p, m, 64);
        if (ov > v || (ov == v && op < p)) { v = ov; p = op; }
      }
      if (lane == 0) { redv[wid] = v; redp[wid] = p; }
      __syncthreads();   // B1

      if (wid == 0) {
        float gv = redv[lane & 7]; int gp = redp[lane & 7];
        #pragma unroll
        for (int m = 1; m < 8; m <<= 1) {
          float ov = __shfl_xor(gv, m, 64);
          int   op = __shfl_xor(gp, m, 64);
          if (ov > gv || (ov == gv && op < gp)) { gv = ov; gp = op; }
        }
        unsigned long long* base = slots + (size_t)(t & 1) * (BATCH * NBLK);
        if (lane == 0) {
          unsigned long long pk = ((unsigned long long)t << 47)
                                | ((unsigned long long)__float_as_uint(gv) << 15)
                                | (unsigned long long)(0x7FFF - gp);
          __hip_atomic_store(base + (b << 3) + bk, pk, __ATOMIC_RELEASE,
                             __HIP_MEMORY_SCOPE_AGENT);
        }
        unsigned long long pk2 = 0;
        if (lane < 8) {
          const unsigned long long* sl = base + (b << 3) + lane;
          do {
            pk2 = __hip_atomic_load(sl, __ATOMIC_ACQUIRE,
                                    __HIP_MEMORY_SCOPE_AGENT);
          } while ((int)(pk2 >> 47) != t);
        }
        #pragma unroll
        for (int m = 1; m < 8; m <<= 1) {
          unsigned long long o = __shfl_xor(pk2, m, 64);
          if (o > pk2) pk2 = o;
        }
        if (lane == 0) bcast = pk2;
      }
      __syncthreads();   // B2

      const unsigned long long wpk = bcast;
      const int gp = 0x7FFF - (int)(wpk & 0x7FFF);
      if (bk == 0 && tid == 0)
        __hip_atomic_store(&s_idx_ws[b * NGROUP + t], gp + 1,
                           __ATOMIC_RELAXED, __HIP_MEMORY_SCOPE_AGENT);
      if (t == NGROUP - 1) break;

      float3 q = c3[gp];
      qx = q.x; qy = q.y; qz = q.z;
      bestv = -1.0f; bestp = 0;
#define UPD8(i) { float t2 = dist2f(x##i, y##i, z##i, qx, qy, qz);           \
    float nd = fminf(d##i, t2); d##i = nd;                                   \
    if (nd > bestv) { bestv = nd; bestp = pbase + (i) * FTPB; } }
      X8(UPD8)
#undef UPD8
    }
    return;
  }

  // ===================== KNN (consumer) =====================
  const int qid = (bx - NFPSBLK) * KNNQPB + wid;   // 0..8191
  const int b   = qid >> 10;
  const float* __restrict__ c = coord + (size_t)b * NPTS * 3;

  // Conservative backoff (~1/3 of estimated publish time), then slow spin.
  const int tq = qid & (NGROUP - 1);
  int enc = __hip_atomic_load(&s_idx_ws[qid], __ATOMIC_RELAXED,
                              __HIP_MEMORY_SCOPE_AGENT);
  for (int i = tq >> 2; i > 0 && enc == 0; --i) {
    __builtin_amdgcn_s_sleep(127);
    enc = __hip_atomic_load(&s_idx_ws[qid], __ATOMIC_RELAXED,
                            __HIP_MEMORY_SCOPE_AGENT);
  }
  while (enc == 0) {
    __builtin_amdgcn_s_sleep(64);
    enc = __hip_atomic_load(&s_idx_ws[qid], __ATOMIC_RELAXED,
                            __HIP_MEMORY_SCOPE_AGENT);
  }
  const int sp = __builtin_amdgcn_readfirstlane(enc - 1);
  const int gq = b * NPTS + sp;
  const float qx = coord[(size_t)gq * 3 + 0];
  const float qy = coord[(size_t)gq * 3 + 1];
  const float qz = coord[(size_t)gq * 3 + 2];

  // Per-lane ascending top-8 (value, index), static indexing only.
  float lv[KLANE]; int li[KLANE];
  #pragma unroll
  for (int j = 0; j < KLANE; ++j) { lv[j] = 1e30f; li[j] = 0x7fffffff; }

  // Branchless sorted insert; strict < keeps equal-distance earlier (lower)
  // indices first, matching lax.top_k tie order.
#define INSERT(D2, P) \
  if ((D2) < lv[KLANE - 1]) { \
    _Pragma("unroll") \
    for (int j = KLANE - 1; j >= 1; --j) { \
      bool up = (D2) < lv[j - 1]; \
      float nv = up ? lv[j - 1] : (((D2) < lv[j]) ? (D2) : lv[j]); \
      int   ni = up ? li[j - 1] : (((D2) < lv[j]) ? (P)  : li[j]); \
      lv[j] = nv; li[j] = ni; \
    } \
    if ((D2) < lv[0]) { lv[0] = (D2); li[0] = (P); } \
  }

  for (int s = 0; s < NPTS / 256; ++s) {   // 128 iterations, 4 pts/lane
    int p = (s << 8) | (lane << 2);
    const float4* c4 = (const float4*)(c + (size_t)p * 3);
    float4 f0 = c4[0], f1 = c4[1], f2 = c4[2];
    float dA = dist2f(f0.x, f0.y, f0.z, qx, qy, qz);
    float dB = dist2f(f0.w, f1.x, f1.y, qx, qy, qz);
    float dC = dist2f(f1.z, f1.w, f2.x, qx, qy, qz);
    float dD = dist2f(f2.y, f2.z, f2.w, qx, qy, qz);
    INSERT(dA, p);
    INSERT(dB, p + 1);
    INSERT(dC, p + 2);
    INSERT(dD, p + 3);
  }
#undef INSERT

  // Extract the 32 globally smallest (ascending, tie -> lower index).
  // Round 0 is the query itself (d2 == 0), excluded from the angle mean
  // like angles[:, :, 1:].
  int nbp = 0;
  for (int r = 0; r < GSIZE; ++r) {
    float mv = lv[0]; int mp = li[0];
    #pragma unroll
    for (int m = 1; m < 64; m <<= 1) {
      float ov = __shfl_xor(mv, m, 64);
      int   op = __shfl_xor(mp, m, 64);
      if (ov < mv || (ov == mv && op < mp)) { mv = ov; mp = op; }
    }
    if (lane == r) nbp = mp;
    if (lv[0] == mv && li[0] == mp) {  // unique winner pops its head
      #pragma unroll
      for (int j = 0; j < KLANE - 1; ++j) { lv[j] = lv[j + 1]; li[j] = li[j + 1]; }
      lv[KLANE - 1] = 1e30f; li[KLANE - 1] = 0x7fffffff;
    }
  }

  // Angle for lanes 1..31: theta = 2*atan2(||a*|b| - |a|*b||, ||a*|b| + |a|*b||)
  const float* aRow = feat + (size_t)gq * FDIM;
  float my_a = (lane < FDIM) ? aRow[lane] : 0.0f;

  float ang = 0.0f;
  if (lane >= 1 && lane < GSIZE) {
    const float4* a4 = (const float4*)aRow;
    const float4* b4 = (const float4*)(feat + ((size_t)b * NPTS + nbp) * FDIM);
    float4 av[FDIM / 4], bv[FDIM / 4];
    float aa = 0.0f, bb = 0.0f;
    #pragma unroll
    for (int k = 0; k < FDIM / 4; ++k) {
      av[k] = a4[k]; bv[k] = b4[k];
      aa += av[k].x * av[k].x + av[k].y * av[k].y + av[k].z * av[k].z + av[k].w * av[k].w;
      bb += bv[k].x * bv[k].x + bv[k].y * bv[k].y + bv[k].z * bv[k].z + bv[k].w * bv[k].w;
    }
    float an = sqrtf(aa), bn = sqrtf(bb);
    float num2 = 0.0f, den2 = 0.0f;
    #pragma unroll
    for (int k = 0; k < FDIM / 4; ++k) {
      float n0 = av[k].x * bn - an * bv[k].x, dd0 = av[k].x * bn + an * bv[k].x;
      float n1 = av[k].y * bn - an * bv[k].y, dd1 = av[k].y * bn + an * bv[k].y;
      float n2 = av[k].z * bn - an * bv[k].z, dd2 = av[k].z * bn + an * bv[k].z;
      float n3 = av[k].w * bn - an * bv[k].w, dd3 = av[k].w * bn + an * bv[k].w;
      num2 += n0 * n0 + n1 * n1 + n2 * n2 + n3 * n3;
      den2 += dd0 * dd0 + dd1 * dd1 + dd2 * dd2 + dd3 * dd3;
    }
    ang = 2.0f * atan2f(sqrtf(num2), sqrtf(den2));
  }

  // Wave sum of the 31 angles -> p_curv everywhere.
  float tot = ang;
  #pragma unroll
  for (int m = 1; m < 64; m <<= 1) tot += __shfl_xor(tot, m, 64);
  float p_curv = tot / 31.0f;

  // Outputs (flat concatenation, all as float32).
  float* out_xyz  = out;                              // 8192*3
  float* out_feat = out + (size_t)BATCH * NGROUP * 3; // 8192*33
  float* out_sw   = out_feat + (size_t)BATCH * NGROUP * (FDIM + 1);
  float* out_lab  = out_sw  + (size_t)BATCH * NGROUP;
  float* out_sif  = out_lab + (size_t)BATCH * NGROUP;

  if (lane < FDIM)  out_feat[(size_t)qid * (FDIM + 1) + lane] = my_a;
  if (lane == FDIM) out_feat[(size_t)qid * (FDIM + 1) + FDIM] = p_curv;
  if (lane == 0) {
    out_xyz[(size_t)qid * 3 + 0] = qx;
    out_xyz[(size_t)qid * 3 + 1] = qy;
    out_xyz[(size_t)qid * 3 + 2] = qz;
    out_sw[qid]  = (p_curv > 0.087266f) ? 1.0f : 0.0f;
    out_lab[qid] = (float)labels[gq];
    out_sif[qid] = (float)gq;   // s_idx + b*N
  }
}

extern "C" void kernel_launch(void* const* d_in, const int* in_sizes, int n_in,
                              void* d_out, int out_size, void* d_ws, size_t ws_size,
                              hipStream_t stream) {
  const float* coord  = (const float*)d_in[0];
  const float* feat   = (const float*)d_in[1];
  const int*   labels = (const int*)d_in[2];

  // ws layout: [2][64] u64 ping-pong slots, then [8192] int s_idx (+1
  // encoded, 0 = unpublished). Both must start zeroed.
  unsigned long long* slots = (unsigned long long*)d_ws;
  int* s_idx_ws = (int*)((char*)d_ws +
                         2 * BATCH * NBLK * sizeof(unsigned long long));
  const size_t zbytes = 2 * BATCH * NBLK * sizeof(unsigned long long)
                      + (size_t)BATCH * NGROUP * sizeof(int);

  hipMemsetAsync(d_ws, 0, zbytes, stream);
  fused_kernel<<<NFPSBLK + NKNNBLK, FTPB, 0, stream>>>(
      coord, feat, labels, slots, s_idx_ws, (float*)d_out);
}